// Round 3
// baseline (370.831 us; speedup 1.0000x reference)
//
#include <hip/hip_runtime.h>
#include <stdint.h>

#define HH 128
#define WW 128
#define NPIX 16384
#define BTN 32
#define CCH 64
#define MPAR 256
#define SENT 16384
#define NSTEPS 40

// ---------------- Kernel A: 4-direction edge masks (LDS-tiled, early-out) ----------------
// bit0 E(0,1), bit1 SW(1,-1), bit2 S(1,0), bit3 SE(1,1)
// Edge condition: aff>0.5 <=> dist<1 <=> s+1e-12 < 1 (monotone transforms; no sqrt/div).
#define ETX 32
#define ETY 8
__global__ __launch_bounds__(256) void edge_kernel(const float* __restrict__ feat,
                                                   unsigned char* __restrict__ mask4) {
  __shared__ float lds[8][308];           // [channel][staged pixel], 306 used
  int blk = blockIdx.x;                   // 2048 blocks
  int b = blk >> 6;
  int t = blk & 63;                       // 16 tile-rows x 4 tile-cols
  int ty0 = (t >> 2) * ETY;
  int tx0 = (t & 3) * ETX;
  int tid = threadIdx.x;
  const float* fb = feat + ((size_t)b << 20);   // b * 16384 * 64

  for (int sp = tid; sp < 306; sp += 256) {
    int gy = ty0 + sp / 34;
    int gx = tx0 - 1 + sp % 34;
    if (gy < HH && (unsigned)gx < (unsigned)WW) {
      const float* pp = fb + (((size_t)(gy << 7) + gx) << 6);
      float4 v0 = *(const float4*)pp;
      float4 v1 = *(const float4*)(pp + 4);
      lds[0][sp] = v0.x; lds[1][sp] = v0.y; lds[2][sp] = v0.z; lds[3][sp] = v0.w;
      lds[4][sp] = v1.x; lds[5][sp] = v1.y; lds[6][sp] = v1.z; lds[7][sp] = v1.w;
    } else {
#pragma unroll
      for (int c = 0; c < 8; ++c) lds[c][sp] = 1e6f;
    }
  }
  __syncthreads();

  int tx = tid & 31, ty = tid >> 5;
  int idx = ty * 34 + tx + 1;
  int gx = tx0 + tx, gy = ty0 + ty;

  float own[8];
#pragma unroll
  for (int c = 0; c < 8; ++c) own[c] = lds[c][idx];
  float a0 = 0.f, a1 = 0.f, a2 = 0.f, a3 = 0.f;
#pragma unroll
  for (int c = 0; c < 8; ++c) {
    float o = own[c];
    float d0 = o - lds[c][idx + 1];     // E
    float d1 = o - lds[c][idx + 33];    // SW
    float d2 = o - lds[c][idx + 34];    // S
    float d3 = o - lds[c][idx + 35];    // SE
    a0 += d0 * d0; a1 += d1 * d1; a2 += d2 * d2; a3 += d3 * d3;
  }

  bool vS = (gy + 1) < HH;
  float acc[4] = {a0, a1, a2, a3};
  bool val[4] = {(gx + 1) < WW, vS && gx >= 1, vS, vS && (gx + 1) < WW};
  const int offp[4] = {1, 127, 128, 129};
  const float* fp = fb + (((size_t)(gy << 7) + gx) << 6);
  unsigned m = 0;
#pragma unroll
  for (int j = 0; j < 4; ++j) {
    if (val[j]) {
      float s = acc[j];
      if (s < 1.0f) {                    // rare: finish channels 8..63 exactly
        const float* np_ = fp + ((size_t)offp[j] << 6);
        for (int c = 8; c < 64; ++c) {
          float d = fp[c] - np_[c];
          s += d * d;
        }
      }
      if (s + 1e-12f < 1.0f) m |= (1u << j);
    }
  }
  mask4[(b << 14) + (gy << 7) + gx] = (unsigned char)m;
}

// ---------------- Kernel B: propagation + relabel ----------------
// e8 bits: b0 NW, b1 N, b2 NE, b3 W, b4 E, b5 SW, b6 S, b7 SE
__global__ __launch_bounds__(1024) void prop_kernel(const unsigned char* __restrict__ mask4g,
                                                    unsigned char* __restrict__ segg) {
  __shared__ __align__(16) unsigned short lab[NPIX];   // 32 KB
  __shared__ __align__(16) unsigned char e8[NPIX];     // 16 KB
  __shared__ __align__(16) unsigned short rnk[NPIX];   // 32 KB
  __shared__ int flags[2];
  __shared__ int wsum[16];
  __shared__ int wexc[16];
  int b = blockIdx.x;
  int tid = threadIdx.x;
  int lane = tid & 63, wid = tid >> 6;

  ((uint4*)e8)[tid] = ((const uint4*)(mask4g + ((size_t)b << 14)))[tid];
  __syncthreads();

  unsigned char tmp[16];
  {
    int base = tid * 16;
#pragma unroll
    for (int i = 0; i < 16; ++i) {
      int p = base + i;
      int y = p >> 7, x = p & (WW - 1);
      unsigned own = e8[p];
      unsigned nw = (y > 0 && x > 0) ? e8[p - 129] : 0;
      unsigned n_ = (y > 0) ? e8[p - 128] : 0;
      unsigned ne = (y > 0 && x < WW - 1) ? e8[p - 127] : 0;
      unsigned w_ = (x > 0) ? e8[p - 1] : 0;
      unsigned v = ((nw >> 3) & 1) | (((n_ >> 2) & 1) << 1) | (((ne >> 1) & 1) << 2) |
                   ((w_ & 1) << 3) | ((own & 1) << 4) | (((own >> 1) & 1) << 5) |
                   (((own >> 2) & 1) << 6) | (((own >> 3) & 1) << 7);
      tmp[i] = (unsigned char)v;
    }
  }
  __syncthreads();
  {
    int base = tid * 16;
#pragma unroll
    for (int i = 0; i < 16; ++i) e8[base + i] = tmp[i];
#pragma unroll
    for (int i = 0; i < 16; ++i) lab[base + i] = (unsigned short)(base + i);
  }
  if (tid == 0) { flags[0] = 0; flags[1] = 0; }
  __syncthreads();

  int x0 = (tid & 31) * 4, y0 = (tid >> 5) * 4;
  int cur[4][4], eb[4][4];
#pragma unroll
  for (int r = 0; r < 4; ++r)
#pragma unroll
    for (int c = 0; c < 4; ++c) {
      cur[r][c] = (y0 + r) * WW + x0 + c;
      eb[r][c] = e8[(y0 + r) * WW + x0 + c];
    }

  for (int it = 0; it < NSTEPS; ++it) {
    int top[6], bot[6], lft[4], rgt[4];
#pragma unroll
    for (int c = 0; c < 6; ++c) {
      top[c] = lab[(((y0 - 1) * WW) + x0 - 1 + c) & (NPIX - 1)];
      bot[c] = lab[(((y0 + 4) * WW) + x0 - 1 + c) & (NPIX - 1)];
    }
#pragma unroll
    for (int r = 0; r < 4; ++r) {
      lft[r] = lab[(((y0 + r) * WW) + x0 - 1) & (NPIX - 1)];
      rgt[r] = lab[(((y0 + r) * WW) + x0 + 4) & (NPIX - 1)];
    }
    int nl[4][4];
    bool ch = false;
#pragma unroll
    for (int r = 0; r < 4; ++r) {
#pragma unroll
      for (int c = 0; c < 4; ++c) {
        int m = cur[r][c];
        int e = eb[r][c];
        int v;
        v = (r > 0) ? ((c > 0) ? cur[r - 1][c - 1] : lft[r - 1]) : top[c];        // NW
        m = min(m, (e & 1) ? v : SENT);
        v = (r > 0) ? cur[r - 1][c] : top[c + 1];                                 // N
        m = min(m, (e & 2) ? v : SENT);
        v = (r > 0) ? ((c < 3) ? cur[r - 1][c + 1] : rgt[r - 1]) : top[c + 2];    // NE
        m = min(m, (e & 4) ? v : SENT);
        v = (c > 0) ? cur[r][c - 1] : lft[r];                                     // W
        m = min(m, (e & 8) ? v : SENT);
        v = (c < 3) ? cur[r][c + 1] : rgt[r];                                     // E
        m = min(m, (e & 16) ? v : SENT);
        v = (r < 3) ? ((c > 0) ? cur[r + 1][c - 1] : lft[r + 1]) : bot[c];        // SW
        m = min(m, (e & 32) ? v : SENT);
        v = (r < 3) ? cur[r + 1][c] : bot[c + 1];                                 // S
        m = min(m, (e & 64) ? v : SENT);
        v = (r < 3) ? ((c < 3) ? cur[r + 1][c + 1] : rgt[r + 1]) : bot[c + 2];    // SE
        m = min(m, (e & 128) ? v : SENT);
        nl[r][c] = m;
        ch |= (m != cur[r][c]);
      }
    }
    __syncthreads();
#pragma unroll
    for (int r = 0; r < 4; ++r) {
      unsigned lo = (unsigned)nl[r][0] | ((unsigned)nl[r][1] << 16);
      unsigned hi = (unsigned)nl[r][2] | ((unsigned)nl[r][3] << 16);
      *((uint2*)&lab[(y0 + r) * WW + x0]) = make_uint2(lo, hi);
    }
    if (ch) flags[it & 1] = 1;
    if (tid == 0) flags[(it + 1) & 1] = 0;
#pragma unroll
    for (int r = 0; r < 4; ++r)
#pragma unroll
      for (int c = 0; c < 4; ++c) cur[r][c] = nl[r][c];
    __syncthreads();
    if (!flags[it & 1]) break;   // converged: remaining iterations are identity (exact)
  }

  __syncthreads();
  ((uint4*)e8)[tid] = make_uint4(0u, 0u, 0u, 0u);
  __syncthreads();
#pragma unroll
  for (int i = 0; i < 16; ++i) {
    int p = tid + i * 1024;
    e8[lab[p]] = 1;
  }
  __syncthreads();
  int pres[16];
  int base = tid * 16;
#pragma unroll
  for (int i = 0; i < 16; ++i) pres[i] = e8[base + i];
  int s_local = 0;
#pragma unroll
  for (int i = 0; i < 16; ++i) s_local += pres[i];
  int inc = s_local;
#pragma unroll
  for (int off = 1; off < 64; off <<= 1) {
    int v = __shfl_up(inc, off, 64);
    if (lane >= off) inc += v;
  }
  if (lane == 63) wsum[wid] = inc;
  __syncthreads();
  if (wid == 0) {
    int tt = (lane < 16) ? wsum[lane] : 0;
    int winc = tt;
#pragma unroll
    for (int off = 1; off < 16; off <<= 1) {
      int v = __shfl_up(winc, off, 64);
      if (lane >= off) winc += v;
    }
    if (lane < 16) wexc[lane] = winc - tt;
  }
  __syncthreads();
  int run = wexc[wid] + (inc - s_local);
#pragma unroll
  for (int i = 0; i < 16; ++i) {
    run += pres[i];
    rnk[base + i] = (unsigned short)(run - 1);
  }
  __syncthreads();
  unsigned char* so = segg + ((size_t)b << 14);
#pragma unroll
  for (int i = 0; i < 16; ++i) {
    int p = tid + i * 1024;
    int sg = rnk[lab[p]];
    so[p] = (unsigned char)min(sg, 255);
  }
}

// ---------------- Kernel D: aggregation (float4 lanes, 8 loads in flight) ----------------
// Lane role: sub = lane>>4 (pixel within 4-pixel group), q = lane&15 (channel quad).
// One wave instruction loads 4 pixels x 256 B = 1 KB contiguous.
#define PXW 128
__global__ __launch_bounds__(256) void agg_kernel(const float* __restrict__ feat,
                                                  const unsigned char* __restrict__ segg,
                                                  float* __restrict__ acc,
                                                  float* __restrict__ cnt) {
  int lane = threadIdx.x & 63;
  int gw = blockIdx.x * 4 + (threadIdx.x >> 6);
  int b = gw >> 7;            // 128 waves per image
  int chunk = gw & 127;
  int basep = (b << 14) + (chunk << 7);
  int sub = lane >> 4;
  int q = lane & 15;
  const unsigned char* sp = segg + basep;
  int s0 = sp[lane];          // coalesced: seg ids of all 128 chunk pixels
  int s1 = sp[64 + lane];
  const float* fp = feat + (((size_t)basep + sub) << 6) + (q << 2);

  float4 sv = make_float4(0.f, 0.f, 0.f, 0.f);
  float4 qv = make_float4(0.f, 0.f, 0.f, 0.f);
  int cacc = 0, curs = -1;

#pragma unroll
  for (int kk = 0; kk < 32; kk += 8) {
    float4 v[8];
#pragma unroll
    for (int u = 0; u < 8; ++u)
      v[u] = *(const float4*)(fp + ((size_t)(kk + u) << 8));   // 8 independent 16B loads
#pragma unroll
    for (int u = 0; u < 8; ++u) {
      int k = kk + u;
      int idx = (k << 2) + sub;                                 // pixel index in chunk
      int sg = __shfl(k < 16 ? s0 : s1, idx & 63, 64);          // k<16 resolves statically
      if (sg != curs) {
        if (curs >= 0) {
          float* a = acc + ((size_t)((b << 8) + curs) << 7) + (q << 2);
          atomicAdd(a + 0, sv.x);  atomicAdd(a + 1, sv.y);
          atomicAdd(a + 2, sv.z);  atomicAdd(a + 3, sv.w);
          atomicAdd(a + 64, qv.x); atomicAdd(a + 65, qv.y);
          atomicAdd(a + 66, qv.z); atomicAdd(a + 67, qv.w);
          if (q == 0) atomicAdd(cnt + (b << 8) + curs, (float)cacc);
        }
        curs = sg;
        sv = make_float4(0.f, 0.f, 0.f, 0.f);
        qv = make_float4(0.f, 0.f, 0.f, 0.f);
        cacc = 0;
      }
      sv.x += v[u].x; sv.y += v[u].y; sv.z += v[u].z; sv.w += v[u].w;
      qv.x += v[u].x * v[u].x; qv.y += v[u].y * v[u].y;
      qv.z += v[u].z * v[u].z; qv.w += v[u].w * v[u].w;
      ++cacc;
    }
  }
  if (curs >= 0) {
    float* a = acc + ((size_t)((b << 8) + curs) << 7) + (q << 2);
    atomicAdd(a + 0, sv.x);  atomicAdd(a + 1, sv.y);
    atomicAdd(a + 2, sv.z);  atomicAdd(a + 3, sv.w);
    atomicAdd(a + 64, qv.x); atomicAdd(a + 65, qv.y);
    atomicAdd(a + 66, qv.z); atomicAdd(a + 67, qv.w);
    if (q == 0) atomicAdd(cnt + (b << 8) + curs, (float)cacc);
  }
}

// ---------------- Kernel E: finalize mean/var in place ----------------
__global__ __launch_bounds__(256) void fin_kernel(float* __restrict__ acc,
                                                  const float* __restrict__ cnt) {
  int gid = blockIdx.x * 256 + threadIdx.x;   // 0..524287
  int bm = gid >> 6, c = gid & 63;
  float* a = acc + ((size_t)bm << 7);
  float s = a[c], q = a[c + 64];
  float n = cnt[bm];
  float denom = fmaxf(n, 1.0f);
  float mean = s / denom;
  float var = fmaxf(q / denom - mean * mean, 0.0f);
  a[c] = mean;
  a[c + 64] = var;
}

extern "C" void kernel_launch(void* const* d_in, const int* in_sizes, int n_in,
                              void* d_out, int out_size, void* d_ws, size_t ws_size,
                              hipStream_t stream) {
  const float* feat = (const float*)d_in[0];
  unsigned char* mask4 = (unsigned char*)d_ws;                       // 512 KB
  unsigned char* segg = mask4 + (size_t)BTN * NPIX;                  // 512 KB
  float* cnt = (float*)(segg + (size_t)BTN * NPIX);                  // 32 KB
  float* acc = (float*)d_out;                                       // sums|sqs -> mean|var

  hipMemsetAsync(d_out, 0, (size_t)out_size * sizeof(float), stream);
  hipMemsetAsync(cnt, 0, (size_t)BTN * MPAR * sizeof(float), stream);

  edge_kernel<<<BTN * 64, 256, 0, stream>>>(feat, mask4);
  prop_kernel<<<BTN, 1024, 0, stream>>>(mask4, segg);
  agg_kernel<<<BTN * NPIX / PXW / 4, 256, 0, stream>>>(feat, segg, acc, cnt);
  fin_kernel<<<BTN * MPAR * CCH / 256, 256, 0, stream>>>(acc, cnt);
}

// Round 4
// 246.203 us; speedup vs baseline: 1.5062x; 1.5062x over previous
//
#include <hip/hip_runtime.h>
#include <stdint.h>

#define HH 128
#define WW 128
#define NPIX 16384
#define BTN 32
#define CCH 64
#define MPAR 256
#define SENT 16384
#define NSTEPS 40

// ---------------- Kernel A: 4-direction edge masks (LDS-tiled, early-out) ----------------
// bit0 E(0,1), bit1 SW(1,-1), bit2 S(1,0), bit3 SE(1,1)
// Edge condition: aff>0.5 <=> dist<1 <=> s+1e-12 < 1 (monotone transforms; no sqrt/div).
#define ETX 32
#define ETY 8
__global__ __launch_bounds__(256) void edge_kernel(const float* __restrict__ feat,
                                                   unsigned char* __restrict__ mask4) {
  __shared__ float lds[8][308];           // [channel][staged pixel], 306 used
  int blk = blockIdx.x;                   // 2048 blocks
  int b = blk >> 6;
  int t = blk & 63;                       // 16 tile-rows x 4 tile-cols
  int ty0 = (t >> 2) * ETY;
  int tx0 = (t & 3) * ETX;
  int tid = threadIdx.x;
  const float* fb = feat + ((size_t)b << 20);   // b * 16384 * 64

  for (int sp = tid; sp < 306; sp += 256) {
    int gy = ty0 + sp / 34;
    int gx = tx0 - 1 + sp % 34;
    if (gy < HH && (unsigned)gx < (unsigned)WW) {
      const float* pp = fb + (((size_t)(gy << 7) + gx) << 6);
      float4 v0 = *(const float4*)pp;
      float4 v1 = *(const float4*)(pp + 4);
      lds[0][sp] = v0.x; lds[1][sp] = v0.y; lds[2][sp] = v0.z; lds[3][sp] = v0.w;
      lds[4][sp] = v1.x; lds[5][sp] = v1.y; lds[6][sp] = v1.z; lds[7][sp] = v1.w;
    } else {
#pragma unroll
      for (int c = 0; c < 8; ++c) lds[c][sp] = 1e6f;
    }
  }
  __syncthreads();

  int tx = tid & 31, ty = tid >> 5;
  int idx = ty * 34 + tx + 1;
  int gx = tx0 + tx, gy = ty0 + ty;

  float own[8];
#pragma unroll
  for (int c = 0; c < 8; ++c) own[c] = lds[c][idx];
  float a0 = 0.f, a1 = 0.f, a2 = 0.f, a3 = 0.f;
#pragma unroll
  for (int c = 0; c < 8; ++c) {
    float o = own[c];
    float d0 = o - lds[c][idx + 1];     // E
    float d1 = o - lds[c][idx + 33];    // SW
    float d2 = o - lds[c][idx + 34];    // S
    float d3 = o - lds[c][idx + 35];    // SE
    a0 += d0 * d0; a1 += d1 * d1; a2 += d2 * d2; a3 += d3 * d3;
  }

  bool vS = (gy + 1) < HH;
  float acc[4] = {a0, a1, a2, a3};
  bool val[4] = {(gx + 1) < WW, vS && gx >= 1, vS, vS && (gx + 1) < WW};
  const int offp[4] = {1, 127, 128, 129};
  const float* fp = fb + (((size_t)(gy << 7) + gx) << 6);
  unsigned m = 0;
#pragma unroll
  for (int j = 0; j < 4; ++j) {
    if (val[j]) {
      float s = acc[j];
      if (s < 1.0f) {                    // rare: finish channels 8..63 exactly
        const float* np_ = fp + ((size_t)offp[j] << 6);
        for (int c = 8; c < 64; ++c) {
          float d = fp[c] - np_[c];
          s += d * d;
        }
      }
      if (s + 1e-12f < 1.0f) m |= (1u << j);
    }
  }
  mask4[(b << 14) + (gy << 7) + gx] = (unsigned char)m;
}

// ---------------- Kernel B: propagation + relabel ----------------
// e8 bits: b0 NW, b1 N, b2 NE, b3 W, b4 E, b5 SW, b6 S, b7 SE
__global__ __launch_bounds__(1024) void prop_kernel(const unsigned char* __restrict__ mask4g,
                                                    unsigned char* __restrict__ segg) {
  __shared__ __align__(16) unsigned short lab[NPIX];   // 32 KB
  __shared__ __align__(16) unsigned char e8[NPIX];     // 16 KB
  __shared__ __align__(16) unsigned short rnk[NPIX];   // 32 KB
  __shared__ int flags[2];
  __shared__ int wsum[16];
  __shared__ int wexc[16];
  int b = blockIdx.x;
  int tid = threadIdx.x;
  int lane = tid & 63, wid = tid >> 6;

  ((uint4*)e8)[tid] = ((const uint4*)(mask4g + ((size_t)b << 14)))[tid];
  __syncthreads();

  unsigned char tmp[16];
  {
    int base = tid * 16;
#pragma unroll
    for (int i = 0; i < 16; ++i) {
      int p = base + i;
      int y = p >> 7, x = p & (WW - 1);
      unsigned own = e8[p];
      unsigned nw = (y > 0 && x > 0) ? e8[p - 129] : 0;
      unsigned n_ = (y > 0) ? e8[p - 128] : 0;
      unsigned ne = (y > 0 && x < WW - 1) ? e8[p - 127] : 0;
      unsigned w_ = (x > 0) ? e8[p - 1] : 0;
      unsigned v = ((nw >> 3) & 1) | (((n_ >> 2) & 1) << 1) | (((ne >> 1) & 1) << 2) |
                   ((w_ & 1) << 3) | ((own & 1) << 4) | (((own >> 1) & 1) << 5) |
                   (((own >> 2) & 1) << 6) | (((own >> 3) & 1) << 7);
      tmp[i] = (unsigned char)v;
    }
  }
  __syncthreads();
  {
    int base = tid * 16;
#pragma unroll
    for (int i = 0; i < 16; ++i) e8[base + i] = tmp[i];
#pragma unroll
    for (int i = 0; i < 16; ++i) lab[base + i] = (unsigned short)(base + i);
  }
  if (tid == 0) { flags[0] = 0; flags[1] = 0; }
  __syncthreads();

  int x0 = (tid & 31) * 4, y0 = (tid >> 5) * 4;
  int cur[4][4], eb[4][4];
#pragma unroll
  for (int r = 0; r < 4; ++r)
#pragma unroll
    for (int c = 0; c < 4; ++c) {
      cur[r][c] = (y0 + r) * WW + x0 + c;
      eb[r][c] = e8[(y0 + r) * WW + x0 + c];
    }

  for (int it = 0; it < NSTEPS; ++it) {
    int top[6], bot[6], lft[4], rgt[4];
#pragma unroll
    for (int c = 0; c < 6; ++c) {
      top[c] = lab[(((y0 - 1) * WW) + x0 - 1 + c) & (NPIX - 1)];
      bot[c] = lab[(((y0 + 4) * WW) + x0 - 1 + c) & (NPIX - 1)];
    }
#pragma unroll
    for (int r = 0; r < 4; ++r) {
      lft[r] = lab[(((y0 + r) * WW) + x0 - 1) & (NPIX - 1)];
      rgt[r] = lab[(((y0 + r) * WW) + x0 + 4) & (NPIX - 1)];
    }
    int nl[4][4];
    bool ch = false;
#pragma unroll
    for (int r = 0; r < 4; ++r) {
#pragma unroll
      for (int c = 0; c < 4; ++c) {
        int m = cur[r][c];
        int e = eb[r][c];
        int v;
        v = (r > 0) ? ((c > 0) ? cur[r - 1][c - 1] : lft[r - 1]) : top[c];        // NW
        m = min(m, (e & 1) ? v : SENT);
        v = (r > 0) ? cur[r - 1][c] : top[c + 1];                                 // N
        m = min(m, (e & 2) ? v : SENT);
        v = (r > 0) ? ((c < 3) ? cur[r - 1][c + 1] : rgt[r - 1]) : top[c + 2];    // NE
        m = min(m, (e & 4) ? v : SENT);
        v = (c > 0) ? cur[r][c - 1] : lft[r];                                     // W
        m = min(m, (e & 8) ? v : SENT);
        v = (c < 3) ? cur[r][c + 1] : rgt[r];                                     // E
        m = min(m, (e & 16) ? v : SENT);
        v = (r < 3) ? ((c > 0) ? cur[r + 1][c - 1] : lft[r + 1]) : bot[c];        // SW
        m = min(m, (e & 32) ? v : SENT);
        v = (r < 3) ? cur[r + 1][c] : bot[c + 1];                                 // S
        m = min(m, (e & 64) ? v : SENT);
        v = (r < 3) ? ((c < 3) ? cur[r + 1][c + 1] : rgt[r + 1]) : bot[c + 2];    // SE
        m = min(m, (e & 128) ? v : SENT);
        nl[r][c] = m;
        ch |= (m != cur[r][c]);
      }
    }
    __syncthreads();
#pragma unroll
    for (int r = 0; r < 4; ++r) {
      unsigned lo = (unsigned)nl[r][0] | ((unsigned)nl[r][1] << 16);
      unsigned hi = (unsigned)nl[r][2] | ((unsigned)nl[r][3] << 16);
      *((uint2*)&lab[(y0 + r) * WW + x0]) = make_uint2(lo, hi);
    }
    if (ch) flags[it & 1] = 1;
    if (tid == 0) flags[(it + 1) & 1] = 0;
#pragma unroll
    for (int r = 0; r < 4; ++r)
#pragma unroll
      for (int c = 0; c < 4; ++c) cur[r][c] = nl[r][c];
    __syncthreads();
    if (!flags[it & 1]) break;   // converged: remaining iterations are identity (exact)
  }

  __syncthreads();
  ((uint4*)e8)[tid] = make_uint4(0u, 0u, 0u, 0u);
  __syncthreads();
#pragma unroll
  for (int i = 0; i < 16; ++i) {
    int p = tid + i * 1024;
    e8[lab[p]] = 1;
  }
  __syncthreads();
  int pres[16];
  int base = tid * 16;
#pragma unroll
  for (int i = 0; i < 16; ++i) pres[i] = e8[base + i];
  int s_local = 0;
#pragma unroll
  for (int i = 0; i < 16; ++i) s_local += pres[i];
  int inc = s_local;
#pragma unroll
  for (int off = 1; off < 64; off <<= 1) {
    int v = __shfl_up(inc, off, 64);
    if (lane >= off) inc += v;
  }
  if (lane == 63) wsum[wid] = inc;
  __syncthreads();
  if (wid == 0) {
    int tt = (lane < 16) ? wsum[lane] : 0;
    int winc = tt;
#pragma unroll
    for (int off = 1; off < 16; off <<= 1) {
      int v = __shfl_up(winc, off, 64);
      if (lane >= off) winc += v;
    }
    if (lane < 16) wexc[lane] = winc - tt;
  }
  __syncthreads();
  int run = wexc[wid] + (inc - s_local);
#pragma unroll
  for (int i = 0; i < 16; ++i) {
    run += pres[i];
    rnk[base + i] = (unsigned short)(run - 1);
  }
  __syncthreads();
  unsigned char* so = segg + ((size_t)b << 14);
#pragma unroll
  for (int i = 0; i < 16; ++i) {
    int p = tid + i * 1024;
    int sg = rnk[lab[p]];
    so[p] = (unsigned char)min(sg, 255);
  }
}

// ---------------- Kernel D: aggregation (lane=channel, 8-deep pipelined loads) ----------
// Flush = 2 fully-coalesced 64-lane vector atomics (R2 structure) — cheap, proven.
// MLP fix: batches of 8 independent dword loads, prefetch next batch during processing.
#define PXW 128
__global__ __launch_bounds__(256) void agg_kernel(const float* __restrict__ feat,
                                                  const unsigned char* __restrict__ segg,
                                                  float* __restrict__ acc,
                                                  float* __restrict__ cnt) {
  int lane = threadIdx.x & 63;
  int gw = blockIdx.x * 4 + (threadIdx.x >> 6);
  int b = gw >> 7;            // 128 waves per image
  int chunk = gw & 127;
  int basep = (b << 14) + (chunk << 7);
  const unsigned char* sp = segg + basep;
  int s0 = sp[lane];          // coalesced: seg ids of all 128 chunk pixels
  int s1 = sp[64 + lane];
  const float* fp = feat + ((size_t)basep << 6) + lane;

  float sacc = 0.f, qacc = 0.f, cacc = 0.f;
  int curs = __shfl(s0, 0, 64);

  float v[8];
#pragma unroll
  for (int u = 0; u < 8; ++u) v[u] = fp[(size_t)u << 6];

  for (int kk = 0; kk < PXW; kk += 8) {
    float w[8];
    if (kk + 8 < PXW) {
#pragma unroll
      for (int u = 0; u < 8; ++u) w[u] = fp[(size_t)(kk + 8 + u) << 6];
    }
#pragma unroll
    for (int u = 0; u < 8; ++u) {
      int k = kk + u;
      int sg = __shfl((k & 64) ? s1 : s0, k & 63, 64);   // wave-uniform broadcast
      if (sg != curs) {                                   // wave-uniform branch
        float* a = acc + ((size_t)((b << 8) + curs) << 7);
        atomicAdd(a + lane, sacc);
        atomicAdd(a + 64 + lane, qacc);
        if (lane == 0) atomicAdd(cnt + (b << 8) + curs, cacc);
        curs = sg; sacc = 0.f; qacc = 0.f; cacc = 0.f;
      }
      sacc += v[u]; qacc += v[u] * v[u]; cacc += 1.f;
    }
#pragma unroll
    for (int u = 0; u < 8; ++u) v[u] = w[u];
  }
  {
    float* a = acc + ((size_t)((b << 8) + curs) << 7);
    atomicAdd(a + lane, sacc);
    atomicAdd(a + 64 + lane, qacc);
    if (lane == 0) atomicAdd(cnt + (b << 8) + curs, cacc);
  }
}

// ---------------- Kernel E: finalize mean/var in place ----------------
__global__ __launch_bounds__(256) void fin_kernel(float* __restrict__ acc,
                                                  const float* __restrict__ cnt) {
  int gid = blockIdx.x * 256 + threadIdx.x;   // 0..524287
  int bm = gid >> 6, c = gid & 63;
  float* a = acc + ((size_t)bm << 7);
  float s = a[c], q = a[c + 64];
  float n = cnt[bm];
  float denom = fmaxf(n, 1.0f);
  float mean = s / denom;
  float var = fmaxf(q / denom - mean * mean, 0.0f);
  a[c] = mean;
  a[c + 64] = var;
}

extern "C" void kernel_launch(void* const* d_in, const int* in_sizes, int n_in,
                              void* d_out, int out_size, void* d_ws, size_t ws_size,
                              hipStream_t stream) {
  const float* feat = (const float*)d_in[0];
  unsigned char* mask4 = (unsigned char*)d_ws;                       // 512 KB
  unsigned char* segg = mask4 + (size_t)BTN * NPIX;                  // 512 KB
  float* cnt = (float*)(segg + (size_t)BTN * NPIX);                  // 32 KB
  float* acc = (float*)d_out;                                       // sums|sqs -> mean|var

  hipMemsetAsync(d_out, 0, (size_t)out_size * sizeof(float), stream);
  hipMemsetAsync(cnt, 0, (size_t)BTN * MPAR * sizeof(float), stream);

  edge_kernel<<<BTN * 64, 256, 0, stream>>>(feat, mask4);
  prop_kernel<<<BTN, 1024, 0, stream>>>(mask4, segg);
  agg_kernel<<<BTN * NPIX / PXW / 4, 256, 0, stream>>>(feat, segg, acc, cnt);
  fin_kernel<<<BTN * MPAR * CCH / 256, 256, 0, stream>>>(acc, cnt);
}

// Round 5
// 229.044 us; speedup vs baseline: 1.6190x; 1.0749x over previous
//
#include <hip/hip_runtime.h>
#include <stdint.h>

#define HH 128
#define WW 128
#define NPIX 16384
#define BTN 32
#define CCH 64
#define MPAR 256
#define SENT 16384
#define NSTEPS 40

// ---------------- Kernel A: 4-direction edge masks (LDS-tiled, early-out) ----------------
// bit0 E(0,1), bit1 SW(1,-1), bit2 S(1,0), bit3 SE(1,1)
// Edge condition: aff>0.5 <=> dist<1 <=> s+1e-12 < 1 (monotone transforms; no sqrt/div).
// Also zeroes acc (d_out) and cnt for the downstream atomic aggregation (saves 2 dispatches).
#define ETX 32
#define ETY 8
__global__ __launch_bounds__(256) void edge_kernel(const float* __restrict__ feat,
                                                   unsigned char* __restrict__ mask4,
                                                   float4* __restrict__ accz,
                                                   float4* __restrict__ cntz) {
  __shared__ float lds[8][308];           // [channel][staged pixel], 306 used
  int blk = blockIdx.x;                   // 2048 blocks
  int tid = threadIdx.x;

  // zero acc: 262144 float4 over 2048 blocks = 128/block; cnt: 2048 float4 = 1/block
  if (tid < 128) accz[blk * 128 + tid] = make_float4(0.f, 0.f, 0.f, 0.f);
  else if (tid == 128) cntz[blk] = make_float4(0.f, 0.f, 0.f, 0.f);

  int b = blk >> 6;
  int t = blk & 63;                       // 16 tile-rows x 4 tile-cols
  int ty0 = (t >> 2) * ETY;
  int tx0 = (t & 3) * ETX;
  const float* fb = feat + ((size_t)b << 20);   // b * 16384 * 64

  for (int sp = tid; sp < 306; sp += 256) {
    int gy = ty0 + sp / 34;
    int gx = tx0 - 1 + sp % 34;
    if (gy < HH && (unsigned)gx < (unsigned)WW) {
      const float* pp = fb + (((size_t)(gy << 7) + gx) << 6);
      float4 v0 = *(const float4*)pp;
      float4 v1 = *(const float4*)(pp + 4);
      lds[0][sp] = v0.x; lds[1][sp] = v0.y; lds[2][sp] = v0.z; lds[3][sp] = v0.w;
      lds[4][sp] = v1.x; lds[5][sp] = v1.y; lds[6][sp] = v1.z; lds[7][sp] = v1.w;
    } else {
#pragma unroll
      for (int c = 0; c < 8; ++c) lds[c][sp] = 1e6f;
    }
  }
  __syncthreads();

  int tx = tid & 31, ty = tid >> 5;
  int idx = ty * 34 + tx + 1;
  int gx = tx0 + tx, gy = ty0 + ty;

  float own[8];
#pragma unroll
  for (int c = 0; c < 8; ++c) own[c] = lds[c][idx];
  float a0 = 0.f, a1 = 0.f, a2 = 0.f, a3 = 0.f;
#pragma unroll
  for (int c = 0; c < 8; ++c) {
    float o = own[c];
    float d0 = o - lds[c][idx + 1];     // E
    float d1 = o - lds[c][idx + 33];    // SW
    float d2 = o - lds[c][idx + 34];    // S
    float d3 = o - lds[c][idx + 35];    // SE
    a0 += d0 * d0; a1 += d1 * d1; a2 += d2 * d2; a3 += d3 * d3;
  }

  bool vS = (gy + 1) < HH;
  float acc[4] = {a0, a1, a2, a3};
  bool val[4] = {(gx + 1) < WW, vS && gx >= 1, vS, vS && (gx + 1) < WW};
  const int offp[4] = {1, 127, 128, 129};
  const float* fp = fb + (((size_t)(gy << 7) + gx) << 6);
  unsigned m = 0;
#pragma unroll
  for (int j = 0; j < 4; ++j) {
    if (val[j]) {
      float s = acc[j];
      if (s < 1.0f) {                    // rare: finish channels 8..63 exactly
        const float* np_ = fp + ((size_t)offp[j] << 6);
        for (int c = 8; c < 64; ++c) {
          float d = fp[c] - np_[c];
          s += d * d;
        }
      }
      if (s + 1e-12f < 1.0f) m |= (1u << j);
    }
  }
  mask4[(b << 14) + (gy << 7) + gx] = (unsigned char)m;
}

// ---------------- Kernel B: propagation + relabel ----------------
// e8 bits: b0 NW, b1 N, b2 NE, b3 W, b4 E, b5 SW, b6 S, b7 SE
__global__ __launch_bounds__(1024) void prop_kernel(const unsigned char* __restrict__ mask4g,
                                                    unsigned char* __restrict__ segg) {
  __shared__ __align__(16) unsigned short lab[NPIX];   // 32 KB
  __shared__ __align__(16) unsigned char e8[NPIX];     // 16 KB
  __shared__ __align__(16) unsigned short rnk[NPIX];   // 32 KB
  __shared__ int flags[2];
  __shared__ int wsum[16];
  __shared__ int wexc[16];
  int b = blockIdx.x;
  int tid = threadIdx.x;
  int lane = tid & 63, wid = tid >> 6;

  ((uint4*)e8)[tid] = ((const uint4*)(mask4g + ((size_t)b << 14)))[tid];
  __syncthreads();

  unsigned char tmp[16];
  {
    int base = tid * 16;
#pragma unroll
    for (int i = 0; i < 16; ++i) {
      int p = base + i;
      int y = p >> 7, x = p & (WW - 1);
      unsigned own = e8[p];
      unsigned nw = (y > 0 && x > 0) ? e8[p - 129] : 0;
      unsigned n_ = (y > 0) ? e8[p - 128] : 0;
      unsigned ne = (y > 0 && x < WW - 1) ? e8[p - 127] : 0;
      unsigned w_ = (x > 0) ? e8[p - 1] : 0;
      unsigned v = ((nw >> 3) & 1) | (((n_ >> 2) & 1) << 1) | (((ne >> 1) & 1) << 2) |
                   ((w_ & 1) << 3) | ((own & 1) << 4) | (((own >> 1) & 1) << 5) |
                   (((own >> 2) & 1) << 6) | (((own >> 3) & 1) << 7);
      tmp[i] = (unsigned char)v;
    }
  }
  __syncthreads();
  {
    int base = tid * 16;
#pragma unroll
    for (int i = 0; i < 16; ++i) e8[base + i] = tmp[i];
#pragma unroll
    for (int i = 0; i < 16; ++i) lab[base + i] = (unsigned short)(base + i);
  }
  if (tid == 0) { flags[0] = 0; flags[1] = 0; }
  __syncthreads();

  int x0 = (tid & 31) * 4, y0 = (tid >> 5) * 4;
  int cur[4][4], eb[4][4];
#pragma unroll
  for (int r = 0; r < 4; ++r)
#pragma unroll
    for (int c = 0; c < 4; ++c) {
      cur[r][c] = (y0 + r) * WW + x0 + c;
      eb[r][c] = e8[(y0 + r) * WW + x0 + c];
    }

  for (int it = 0; it < NSTEPS; ++it) {
    int top[6], bot[6], lft[4], rgt[4];
#pragma unroll
    for (int c = 0; c < 6; ++c) {
      top[c] = lab[(((y0 - 1) * WW) + x0 - 1 + c) & (NPIX - 1)];
      bot[c] = lab[(((y0 + 4) * WW) + x0 - 1 + c) & (NPIX - 1)];
    }
#pragma unroll
    for (int r = 0; r < 4; ++r) {
      lft[r] = lab[(((y0 + r) * WW) + x0 - 1) & (NPIX - 1)];
      rgt[r] = lab[(((y0 + r) * WW) + x0 + 4) & (NPIX - 1)];
    }
    int nl[4][4];
    bool ch = false;
#pragma unroll
    for (int r = 0; r < 4; ++r) {
#pragma unroll
      for (int c = 0; c < 4; ++c) {
        int m = cur[r][c];
        int e = eb[r][c];
        int v;
        v = (r > 0) ? ((c > 0) ? cur[r - 1][c - 1] : lft[r - 1]) : top[c];        // NW
        m = min(m, (e & 1) ? v : SENT);
        v = (r > 0) ? cur[r - 1][c] : top[c + 1];                                 // N
        m = min(m, (e & 2) ? v : SENT);
        v = (r > 0) ? ((c < 3) ? cur[r - 1][c + 1] : rgt[r - 1]) : top[c + 2];    // NE
        m = min(m, (e & 4) ? v : SENT);
        v = (c > 0) ? cur[r][c - 1] : lft[r];                                     // W
        m = min(m, (e & 8) ? v : SENT);
        v = (c < 3) ? cur[r][c + 1] : rgt[r];                                     // E
        m = min(m, (e & 16) ? v : SENT);
        v = (r < 3) ? ((c > 0) ? cur[r + 1][c - 1] : lft[r + 1]) : bot[c];        // SW
        m = min(m, (e & 32) ? v : SENT);
        v = (r < 3) ? cur[r + 1][c] : bot[c + 1];                                 // S
        m = min(m, (e & 64) ? v : SENT);
        v = (r < 3) ? ((c < 3) ? cur[r + 1][c + 1] : rgt[r + 1]) : bot[c + 2];    // SE
        m = min(m, (e & 128) ? v : SENT);
        nl[r][c] = m;
        ch |= (m != cur[r][c]);
      }
    }
    __syncthreads();
#pragma unroll
    for (int r = 0; r < 4; ++r) {
      unsigned lo = (unsigned)nl[r][0] | ((unsigned)nl[r][1] << 16);
      unsigned hi = (unsigned)nl[r][2] | ((unsigned)nl[r][3] << 16);
      *((uint2*)&lab[(y0 + r) * WW + x0]) = make_uint2(lo, hi);
    }
    if (ch) flags[it & 1] = 1;
    if (tid == 0) flags[(it + 1) & 1] = 0;
#pragma unroll
    for (int r = 0; r < 4; ++r)
#pragma unroll
      for (int c = 0; c < 4; ++c) cur[r][c] = nl[r][c];
    __syncthreads();
    if (!flags[it & 1]) break;   // converged: remaining iterations are identity (exact)
  }

  __syncthreads();
  ((uint4*)e8)[tid] = make_uint4(0u, 0u, 0u, 0u);
  __syncthreads();
#pragma unroll
  for (int i = 0; i < 16; ++i) {
    int p = tid + i * 1024;
    e8[lab[p]] = 1;
  }
  __syncthreads();
  int pres[16];
  int base = tid * 16;
#pragma unroll
  for (int i = 0; i < 16; ++i) pres[i] = e8[base + i];
  int s_local = 0;
#pragma unroll
  for (int i = 0; i < 16; ++i) s_local += pres[i];
  int inc = s_local;
#pragma unroll
  for (int off = 1; off < 64; off <<= 1) {
    int v = __shfl_up(inc, off, 64);
    if (lane >= off) inc += v;
  }
  if (lane == 63) wsum[wid] = inc;
  __syncthreads();
  if (wid == 0) {
    int tt = (lane < 16) ? wsum[lane] : 0;
    int winc = tt;
#pragma unroll
    for (int off = 1; off < 16; off <<= 1) {
      int v = __shfl_up(winc, off, 64);
      if (lane >= off) winc += v;
    }
    if (lane < 16) wexc[lane] = winc - tt;
  }
  __syncthreads();
  int run = wexc[wid] + (inc - s_local);
#pragma unroll
  for (int i = 0; i < 16; ++i) {
    run += pres[i];
    rnk[base + i] = (unsigned short)(run - 1);
  }
  __syncthreads();
  unsigned char* so = segg + ((size_t)b << 14);
#pragma unroll
  for (int i = 0; i < 16; ++i) {
    int p = tid + i * 1024;
    int sg = rnk[lab[p]];
    so[p] = (unsigned char)min(sg, 255);
  }
}

// ---------------- Kernel D: aggregation (lane=channel, 32-deep pipelined loads) --------
// Flush = 2 fully-coalesced 64-lane vector atomics; seg broadcast via readlane (SGPR) so
// the flush branch is a scalar s_cbranch. 32 loads in flight amortize the ~900-cyc HBM
// latency over 32 pixels instead of 8.
#define PXW 128
__global__ __launch_bounds__(256) void agg_kernel(const float* __restrict__ feat,
                                                  const unsigned char* __restrict__ segg,
                                                  float* __restrict__ acc,
                                                  float* __restrict__ cnt) {
  int lane = threadIdx.x & 63;
  int gw = blockIdx.x * 4 + (threadIdx.x >> 6);
  int b = gw >> 7;            // 128 waves per image
  int chunk = gw & 127;
  int basep = (b << 14) + (chunk << 7);
  const unsigned char* sp = segg + basep;
  int s0 = sp[lane];          // coalesced: seg ids of all 128 chunk pixels
  int s1 = sp[64 + lane];
  const float* fp = feat + ((size_t)basep << 6) + lane;

  float sacc = 0.f, qacc = 0.f, cacc = 0.f;
  int curs = __builtin_amdgcn_readlane(s0, 0);

  float v[32];
#pragma unroll
  for (int u = 0; u < 32; ++u) v[u] = fp[(size_t)u << 6];

#pragma unroll
  for (int kk = 0; kk < PXW; kk += 32) {
    float w[32];
    if (kk + 32 < PXW) {
#pragma unroll
      for (int u = 0; u < 32; ++u) w[u] = fp[(size_t)(kk + 32 + u) << 6];
    }
#pragma unroll
    for (int u = 0; u < 32; ++u) {
      int k = kk + u;
      int sg = __builtin_amdgcn_readlane((k & 64) ? s1 : s0, k & 63);  // SGPR broadcast
      if (sg != curs) {                                                // scalar branch
        float* a = acc + ((size_t)((b << 8) + curs) << 7);
        atomicAdd(a + lane, sacc);
        atomicAdd(a + 64 + lane, qacc);
        if (lane == 0) atomicAdd(cnt + (b << 8) + curs, cacc);
        curs = sg; sacc = 0.f; qacc = 0.f; cacc = 0.f;
      }
      sacc += v[u]; qacc += v[u] * v[u]; cacc += 1.f;
    }
#pragma unroll
    for (int u = 0; u < 32; ++u) v[u] = w[u];
  }
  {
    float* a = acc + ((size_t)((b << 8) + curs) << 7);
    atomicAdd(a + lane, sacc);
    atomicAdd(a + 64 + lane, qacc);
    if (lane == 0) atomicAdd(cnt + (b << 8) + curs, cacc);
  }
}

// ---------------- Kernel E: finalize mean/var in place ----------------
__global__ __launch_bounds__(256) void fin_kernel(float* __restrict__ acc,
                                                  const float* __restrict__ cnt) {
  int gid = blockIdx.x * 256 + threadIdx.x;   // 0..524287
  int bm = gid >> 6, c = gid & 63;
  float* a = acc + ((size_t)bm << 7);
  float s = a[c], q = a[c + 64];
  float n = cnt[bm];
  float denom = fmaxf(n, 1.0f);
  float mean = s / denom;
  float var = fmaxf(q / denom - mean * mean, 0.0f);
  a[c] = mean;
  a[c + 64] = var;
}

extern "C" void kernel_launch(void* const* d_in, const int* in_sizes, int n_in,
                              void* d_out, int out_size, void* d_ws, size_t ws_size,
                              hipStream_t stream) {
  const float* feat = (const float*)d_in[0];
  unsigned char* mask4 = (unsigned char*)d_ws;                       // 512 KB
  unsigned char* segg = mask4 + (size_t)BTN * NPIX;                  // 512 KB
  float* cnt = (float*)(segg + (size_t)BTN * NPIX);                  // 32 KB
  float* acc = (float*)d_out;                                       // sums|sqs -> mean|var

  edge_kernel<<<BTN * 64, 256, 0, stream>>>(feat, mask4, (float4*)acc, (float4*)cnt);
  prop_kernel<<<BTN, 1024, 0, stream>>>(mask4, segg);
  agg_kernel<<<BTN * NPIX / PXW / 4, 256, 0, stream>>>(feat, segg, acc, cnt);
  fin_kernel<<<BTN * MPAR * CCH / 256, 256, 0, stream>>>(acc, cnt);
}